// Round 4
// baseline (772.784 us; speedup 1.0000x reference)
//
#include <hip/hip_runtime.h>
#include <hip/hip_bf16.h>
#include <math.h>

// DeepSeekMoE: T=4096, H=1024, F=4096, E=8, top-2 sigmoid routing.
// Round 4: 8-phase counted-vmcnt grouped GEMM (T3+T4+T5+T2-swizzle), both GEMMs.

#define T_TOK 4096
#define H_DIM 1024
#define F_DIM 4096
#define NEXP  8
#define RT    (2 * T_TOK)
#define RPAD  512

typedef __bf16 bf16_t;
typedef __bf16 bf16x8 __attribute__((ext_vector_type(8)));
typedef float  f32x4  __attribute__((ext_vector_type(4)));
typedef unsigned short u16x8 __attribute__((ext_vector_type(8)));

#define CFENCE() asm volatile("" ::: "memory")
#define BAR()    do { CFENCE(); __builtin_amdgcn_s_barrier(); CFENCE(); } while (0)
#define LGKM0()  asm volatile("s_waitcnt lgkmcnt(0)" ::: "memory")
#define VM4()    asm volatile("s_waitcnt vmcnt(4)" ::: "memory")

__device__ __forceinline__ unsigned short f2bf(float f) {
  union { bf16_t b; unsigned short u; } cv;
  cv.b = (bf16_t)f;
  return cv.u;
}

__device__ __forceinline__ float gelu_exact(float v) {
  return 0.5f * v * (1.0f + erff(v * 0.70710678118654752f));
}

// bijective XCD swizzle (m204)
__device__ __forceinline__ int xcd_swizzle(int orig, int nwg) {
  const int q = nwg >> 3, r = nwg & 7;
  const int xcd = orig & 7, idx = orig >> 3;
  return (xcd < r ? xcd * (q + 1) : r * (q + 1) + (xcd - r) * q) + idx;
}

// LDS bank swizzle: XOR 16B-chunk index (2b) with row-derived value (2-way = free)
__device__ __forceinline__ int swz(int row) {
  return (row & 3) ^ ((row >> 2) & 1);
}

// ---------------------------------------------------------------- small kernels

__global__ void zero_kernel(int* p) {
  if (threadIdx.x < 16) p[threadIdx.x] = 0;
}

// all four weight tensors -> contiguous bf16 dst (w1s|w2s|w1e|w2e)
__global__ void convert4_kernel(const float* __restrict__ s0, const float* __restrict__ s1,
                                const float* __restrict__ s2, const float* __restrict__ s3,
                                unsigned short* __restrict__ dst) {
  const long N0 = (long)F_DIM * H_DIM / 8;              // 524288
  const long N1 = N0 + (long)H_DIM * F_DIM / 8;         // 1048576
  const long N2 = N1 + (long)NEXP * F_DIM * H_DIM / 8;  // 5242880
  const long NT = N2 + (long)NEXP * H_DIM * F_DIM / 8;  // 9437184
  long i = (long)blockIdx.x * blockDim.x + threadIdx.x;
  const long stride = (long)gridDim.x * blockDim.x;
  for (; i < NT; i += stride) {
    const float* s; long j;
    if (i < N0)      { s = s0; j = i; }
    else if (i < N1) { s = s1; j = i - N0; }
    else if (i < N2) { s = s2; j = i - N1; }
    else             { s = s3; j = i - N2; }
    const f32x4* sp = (const f32x4*)s + j * 2;
    f32x4 v0 = sp[0], v1 = sp[1];
    u16x8 o;
    #pragma unroll
    for (int k = 0; k < 4; ++k) { o[k] = f2bf(v0[k]); o[4 + k] = f2bf(v1[k]); }
    *(u16x8*)(dst + i * 8) = o;
  }
}

// one wave per token: 8 gate scores -> sigmoid -> top2; also emits x in bf16
__global__ void gate_kernel(const float* __restrict__ x, const float* __restrict__ gw,
                            const float* __restrict__ gb, const float* __restrict__ rb,
                            unsigned short* __restrict__ x_bf,
                            int* __restrict__ tok_e, float* __restrict__ tok_w,
                            int* __restrict__ counts) {
  int tkn = blockIdx.x;
  int lane = threadIdx.x;
  float acc[NEXP];
  #pragma unroll
  for (int e = 0; e < NEXP; ++e) acc[e] = 0.f;
  const float* xr = x + (long)tkn * H_DIM;
  unsigned short* xbr = x_bf + (long)tkn * H_DIM;
  for (int k = lane; k < H_DIM; k += 64) {
    float xv = xr[k];
    xbr[k] = f2bf(xv);
    #pragma unroll
    for (int e = 0; e < NEXP; ++e) acc[e] += xv * gw[e * H_DIM + k];
  }
  #pragma unroll
  for (int off = 32; off > 0; off >>= 1) {
    #pragma unroll
    for (int e = 0; e < NEXP; ++e) acc[e] += __shfl_xor(acc[e], off, 64);
  }
  if (lane == 0) {
    float s[NEXP];
    #pragma unroll
    for (int e = 0; e < NEXP; ++e)
      s[e] = 1.f / (1.f + expf(-(acc[e] + gb[e] + rb[e])));
    int e0 = 0;
    #pragma unroll
    for (int e = 1; e < NEXP; ++e) if (s[e] > s[e0]) e0 = e;
    int e1 = (e0 == 0) ? 1 : 0;
    #pragma unroll
    for (int e = 0; e < NEXP; ++e) if (e != e0 && e != e1 && s[e] > s[e1]) e1 = e;
    tok_e[2 * tkn] = e0;  tok_e[2 * tkn + 1] = e1;
    tok_w[2 * tkn] = s[e0]; tok_w[2 * tkn + 1] = s[e1];
    atomicAdd(&counts[e0], 1);
    atomicAdd(&counts[e1], 1);
  }
}

__global__ void scan_kernel(const int* __restrict__ counts, int* __restrict__ offs) {
  if (threadIdx.x == 0) {
    int o = 0;
    for (int e = 0; e < NEXP; ++e) { offs[e] = o; o += counts[e]; }
  }
}

__global__ void build_kernel(const int* __restrict__ tok_e, const float* __restrict__ tok_w,
                             const int* __restrict__ offs, int* __restrict__ cursor,
                             int* __restrict__ btok, float* __restrict__ bw,
                             int* __restrict__ tokpos) {
  int tkn = blockIdx.x * blockDim.x + threadIdx.x;
  if (tkn >= T_TOK) return;
  #pragma unroll
  for (int k = 0; k < 2; ++k) {
    int e = tok_e[2 * tkn + k];
    int p = offs[e] + atomicAdd(&cursor[e], 1);
    btok[p] = tkn;
    bw[p] = tok_w[2 * tkn + k];
    tokpos[2 * tkn + k] = p;
  }
}

__global__ void gather_kernel(const float* __restrict__ x, const int* __restrict__ btok,
                              unsigned short* __restrict__ gx) {
  int p = blockIdx.x, tid = threadIdx.x;
  int tkn = btok[p];
  const f32x4* s = (const f32x4*)(x + (long)tkn * H_DIM);
  f32x4 v0 = s[tid * 2], v1 = s[tid * 2 + 1];
  u16x8 o;
  #pragma unroll
  for (int j = 0; j < 4; ++j) { o[j] = f2bf(v0[j]); o[4 + j] = f2bf(v1[j]); }
  *(u16x8*)(gx + (long)p * H_DIM + tid * 8) = o;
}

__global__ void combine_kernel(float* __restrict__ out, const float* __restrict__ rout,
                               const int* __restrict__ tokpos) {
  int tkn = blockIdx.x, c = threadIdx.x;
  int p0 = tokpos[2 * tkn], p1 = tokpos[2 * tkn + 1];
  f32x4* o = (f32x4*)out + (long)tkn * 256;
  const f32x4* a = (const f32x4*)rout + (long)p0 * 256;
  const f32x4* b = (const f32x4*)rout + (long)p1 * 256;
  o[c] = o[c] + a[c] + b[c];
}

// ---------------------------------------------------------------- 8-phase grouped GEMM
// C[M,N] = A[M,K] @ B[N,K]^T (+bias, epilogue per MODE).
// 256x256 tile, BK=64 (2 k-slices of 32), 8 waves (2Mx4N), 128 KB LDS dbuf.
// grid.z: 0..7 experts, 8 shared. MODE 1: gelu->bf16. MODE 2: [*rowscale]->f32.
//
// Pipeline (per K-tile, 4 phases; stage slots of tile t+1 into buf^1):
//  PH_A: rd a[0..3]ks0 + b[0..3]ks0 | stage A.ks0(t+1) | bar,lgkm0 | 16 MFMA | bar
//  PH_B: rd a[4..7]ks0              | stage B.ks0(t+1) | vmcnt(4),bar,lgkm0 | 16 MFMA | bar
//  PH_C: rd a[0..3]ks1 + b[0..3]ks1 | stage A.ks1(t+1) | bar,lgkm0 | 16 MFMA | bar
//  PH_D: rd a[4..7]ks1              | stage B.ks1(t+1) | vmcnt(4),bar,lgkm0 | 16 MFMA | bar
// vmcnt(4): loads retire in order; the 4 newest (2 slots just issued) may pend,
// all older slots -- exactly what the next two phases read -- are complete.
template<int MODE>
__global__ __launch_bounds__(512, 2)
void gemm8p(const unsigned short* __restrict__ Ash, const unsigned short* __restrict__ Art,
            const unsigned short* __restrict__ Wsh, const unsigned short* __restrict__ Wrt,
            const float* __restrict__ bsh, const float* __restrict__ brt,
            void* __restrict__ Csh, void* __restrict__ Crt,
            const float* __restrict__ bwgt,
            const int* __restrict__ cnts, const int* __restrict__ offs,
            int N, int K) {
  // [buf][mat][ks][row][col] : 2*2*2*256*32*2B = 128 KB
  __shared__ __align__(16) unsigned short lds[2][2][2][256][32];
  const int gxd = gridDim.x;
  const int nwg = gxd * gridDim.y;
  const int wg = xcd_swizzle(blockIdx.y * gxd + blockIdx.x, nwg);
  const int mb = wg % gxd, nb = wg / gxd;
  const int z = blockIdx.z;

  const unsigned short* A;
  const unsigned short* Bp;
  const float* bias;
  const float* rs = nullptr;
  char* Cb;
  int mcnt;
  if (z == NEXP) {
    A = Ash; Bp = Wsh; bias = bsh; Cb = (char*)Csh; mcnt = T_TOK;
  } else {
    const int off = offs[z];
    mcnt = cnts[z];
    A = Art + (long)off * K;
    Bp = Wrt + (long)z * N * K;
    bias = brt + z * N;
    if (MODE == 1) Cb = (char*)Crt + (long)off * N * 2;
    else         { Cb = (char*)Crt + (long)off * N * 4; rs = bwgt + off; }
  }
  if (mb * 256 >= mcnt) return;

  const int t = threadIdx.x;
  const int l = t & 63;
  const int w = t >> 6;                       // 8 waves: 2M x 4N
  const int wr = (w >> 2) * 128, wc = (w & 3) * 64;
  const int lr = l & 15;
  const int c2r = l >> 4;                     // 16B chunk within 32-col slice

  f32x4 acc[8][4] = {};
  const int nkt = K >> 6;

  // frag byte offsets within [row][32] slot (swizzled chunk)
  int aoff[8], boff[4];
  #pragma unroll
  for (int m = 0; m < 8; ++m) {
    const int r = wr + m * 16 + lr;
    aoff[m] = r * 64 + ((c2r ^ swz(r)) * 16);
  }
  #pragma unroll
  for (int n = 0; n < 4; ++n) {
    const int r = wc + n * 16 + lr;
    boff[n] = r * 64 + ((c2r ^ swz(r)) * 16);
  }

  auto stage = [&](int mat, int ks, int kt, int buf) {
    const unsigned short* G = mat ? Bp : A;
    const int rbase = mat ? nb * 256 : mb * 256;
    #pragma unroll
    for (int i = 0; i < 2; ++i) {
      const int row = i * 128 + (t >> 2);
      const int c2 = (t & 3) ^ swz(row);
      const unsigned short* g = G + (long)(rbase + row) * K + kt * 64 + ks * 32 + c2 * 8;
      unsigned short* d = &lds[buf][mat][ks][0][0] + i * 4096 + t * 8;
      __builtin_amdgcn_global_load_lds((const __attribute__((address_space(1))) unsigned int*)g,
                                       (__attribute__((address_space(3))) unsigned int*)d, 16, 0, 0);
    }
  };

  bf16x8 aF[8], bF[4];
  auto rdA4 = [&](int buf, int ks, int m0) {
    const char* p = (const char*)&lds[0][0][0][0][0] + buf * 65536 + ks * 16384;
    #pragma unroll
    for (int m = 0; m < 4; ++m) aF[m0 + m] = *(const bf16x8*)(p + aoff[m0 + m]);
  };
  auto rdB4 = [&](int buf, int ks) {
    const char* p = (const char*)&lds[0][0][0][0][0] + buf * 65536 + 32768 + ks * 16384;
    #pragma unroll
    for (int n = 0; n < 4; ++n) bF[n] = *(const bf16x8*)(p + boff[n]);
  };
  auto mm4 = [&](int m0) {
    #pragma unroll
    for (int m = 0; m < 4; ++m)
      #pragma unroll
      for (int n = 0; n < 4; ++n)
        acc[m0 + m][n] = __builtin_amdgcn_mfma_f32_16x16x32_bf16(aF[m0 + m], bF[n], acc[m0 + m][n], 0, 0, 0);
  };

  // prologue: tile 0 -> buf0; A.ks0,B.ks0 (oldest 4) must land; A.ks1,B.ks1 may pend
  stage(0, 0, 0, 0); stage(1, 0, 0, 0); stage(0, 1, 0, 0); stage(1, 1, 0, 0);
  VM4();
  BAR();

  for (int kt = 0; kt < nkt; ++kt) {
    const int buf = kt & 1, nbf = buf ^ 1;
    const int ktp = (kt + 1 < nkt) ? kt + 1 : kt;   // clamped prefetch (dead tile ok)
    // PH_A
    rdA4(buf, 0, 0); rdB4(buf, 0);
    stage(0, 0, ktp, nbf);
    BAR(); LGKM0();
    __builtin_amdgcn_s_setprio(1); mm4(0); __builtin_amdgcn_s_setprio(0);
    BAR();
    // PH_B
    rdA4(buf, 0, 4);
    stage(1, 0, ktp, nbf);
    VM4();
    BAR(); LGKM0();
    __builtin_amdgcn_s_setprio(1); mm4(4); __builtin_amdgcn_s_setprio(0);
    BAR();
    // PH_C
    rdA4(buf, 1, 0); rdB4(buf, 1);
    stage(0, 1, ktp, nbf);
    BAR(); LGKM0();
    __builtin_amdgcn_s_setprio(1); mm4(0); __builtin_amdgcn_s_setprio(0);
    BAR();
    // PH_D
    rdA4(buf, 1, 4);
    stage(1, 1, ktp, nbf);
    VM4();
    BAR(); LGKM0();
    __builtin_amdgcn_s_setprio(1); mm4(4); __builtin_amdgcn_s_setprio(0);
    BAR();
  }

  // epilogue: C/D layout col=lane&15, row=(lane>>4)*4+j (m89-verified)
  #pragma unroll
  for (int m = 0; m < 8; ++m) {
    #pragma unroll
    for (int n = 0; n < 4; ++n) {
      const int col = nb * 256 + wc + n * 16 + lr;
      const float bc = bias[col];
      #pragma unroll
      for (int j = 0; j < 4; ++j) {
        const int lrow = mb * 256 + wr + m * 16 + (l >> 4) * 4 + j;
        if (lrow >= mcnt) continue;
        float v = acc[m][n][j] + bc;
        if (MODE == 1) {
          ((unsigned short*)Cb)[(long)lrow * N + col] = f2bf(gelu_exact(v));
        } else {
          if (z != NEXP) v *= rs[lrow];
          ((float*)Cb)[(long)lrow * N + col] = v;
        }
      }
    }
  }
}

// ---------------------------------------------------------------- host

extern "C" void kernel_launch(void* const* d_in, const int* in_sizes, int n_in,
                              void* d_out, int out_size, void* d_ws, size_t ws_size,
                              hipStream_t stream) {
  const float* x   = (const float*)d_in[0];
  const float* gw  = (const float*)d_in[1];
  const float* gb  = (const float*)d_in[2];
  const float* rb  = (const float*)d_in[3];
  const float* sw1 = (const float*)d_in[4];
  const float* sb1 = (const float*)d_in[5];
  const float* sw2 = (const float*)d_in[6];
  const float* sb2 = (const float*)d_in[7];
  const float* ew1 = (const float*)d_in[8];
  const float* eb1 = (const float*)d_in[9];
  const float* ew2 = (const float*)d_in[10];
  const float* eb2 = (const float*)d_in[11];

  char* wsp = (char*)d_ws;
  size_t o = 0;
  auto alloc = [&](size_t b) -> void* {
    void* p = wsp + o;
    o = (o + b + 255) & ~(size_t)255;
    return p;
  };
  unsigned short* x_bf = (unsigned short*)alloc((size_t)T_TOK * H_DIM * 2);
  // w1s|w2s|w1e|w2e must stay contiguous (convert4 writes one flat dst)
  unsigned short* w1s  = (unsigned short*)alloc((size_t)F_DIM * H_DIM * 2);
  unsigned short* w2s  = (unsigned short*)alloc((size_t)H_DIM * F_DIM * 2);
  unsigned short* w1e  = (unsigned short*)alloc((size_t)NEXP * F_DIM * H_DIM * 2);
  unsigned short* w2e  = (unsigned short*)alloc((size_t)NEXP * H_DIM * F_DIM * 2);
  unsigned short* gx   = (unsigned short*)alloc((size_t)(RT + RPAD) * H_DIM * 2);
  unsigned short* hbuf = (unsigned short*)alloc((size_t)(T_TOK + RT + RPAD) * F_DIM * 2);
  float* rout          = (float*)alloc((size_t)RT * H_DIM * 4);
  int*   tok_e  = (int*)alloc(2 * T_TOK * 4);
  float* tok_w  = (float*)alloc(2 * T_TOK * 4);
  int*   tokpos = (int*)alloc(2 * T_TOK * 4);
  int*   btok   = (int*)alloc(RT * 4);
  float* bw     = (float*)alloc(RT * 4);
  int*   meta   = (int*)alloc(1024);
  int* counts = meta, *cursor = meta + 8, *offs = meta + 16;
  (void)ws_size; (void)in_sizes; (void)n_in; (void)out_size;

  float* out = (float*)d_out;

  zero_kernel<<<1, 64, 0, stream>>>(meta);
  convert4_kernel<<<4096, 256, 0, stream>>>(sw1, sw2, ew1, ew2, w1s);
  gate_kernel<<<T_TOK, 64, 0, stream>>>(x, gw, gb, rb, x_bf, tok_e, tok_w, counts);
  scan_kernel<<<1, 1, 0, stream>>>(counts, offs);
  build_kernel<<<T_TOK / 256, 256, 0, stream>>>(tok_e, tok_w, offs, cursor, btok, bw, tokpos);
  gather_kernel<<<RT, 128, 0, stream>>>(x, btok, gx);

  // GEMM1: K=1024, N=4096. shared h rows [0,T); routed h rows [T, T+RT)
  gemm8p<1><<<dim3(T_TOK / 256, F_DIM / 256, NEXP + 1), 512, 0, stream>>>(
      x_bf, gx, w1s, w1e, sb1, eb1,
      hbuf, hbuf + (size_t)T_TOK * F_DIM, nullptr, counts, offs, F_DIM, H_DIM);

  // GEMM2: K=4096, N=1024. shared -> out, routed -> rout (scaled by bw)
  gemm8p<2><<<dim3(T_TOK / 256, H_DIM / 256, NEXP + 1), 512, 0, stream>>>(
      hbuf, hbuf + (size_t)T_TOK * F_DIM, w2s, w2e, sb2, eb2,
      out, rout, bw, counts, offs, H_DIM, F_DIM);

  combine_kernel<<<T_TOK, 256, 0, stream>>>(out, rout, tokpos);
}

// Round 5
// 751.183 us; speedup vs baseline: 1.0288x; 1.0288x over previous
//
#include <hip/hip_runtime.h>
#include <hip/hip_bf16.h>
#include <math.h>

// DeepSeekMoE: T=4096, H=1024, F=4096, E=8, top-2 sigmoid routing.
// Round 5: revert to round-3 2-phase GEMMs (8-phase port regressed: 1 blk/CU,
// shallow pipeline). Kill the weight-convert pass by fusing fp32->bf16 into
// the GEMM B-staging (T14 async-split: load early, cvt+ds_write late).

#define T_TOK 4096
#define H_DIM 1024
#define F_DIM 4096
#define NEXP  8
#define RT    (2 * T_TOK)
#define RPAD  512

typedef __bf16 bf16_t;
typedef __bf16 bf16x8 __attribute__((ext_vector_type(8)));
typedef float  f32x4  __attribute__((ext_vector_type(4)));
typedef unsigned short u16x8 __attribute__((ext_vector_type(8)));

__device__ __forceinline__ unsigned short f2bf(float f) {
  union { bf16_t b; unsigned short u; } cv;
  cv.b = (bf16_t)f;   // fptrunc float->bfloat is RNE (matches convert-pass values)
  return cv.u;
}

__device__ __forceinline__ float gelu_exact(float v) {
  return 0.5f * v * (1.0f + erff(v * 0.70710678118654752f));
}

// bijective XCD swizzle (m204)
__device__ __forceinline__ int xcd_swizzle(int orig, int nwg) {
  const int q = nwg >> 3, r = nwg & 7;
  const int xcd = orig & 7, idx = orig >> 3;
  return (xcd < r ? xcd * (q + 1) : r * (q + 1) + (xcd - r) * q) + idx;
}

// ---------------------------------------------------------------- small kernels

__global__ void zero_kernel(int* p) {
  if (threadIdx.x < 16) p[threadIdx.x] = 0;
}

// one wave per token: 8 gate scores -> sigmoid -> top2; also emits x in bf16
__global__ void gate_kernel(const float* __restrict__ x, const float* __restrict__ gw,
                            const float* __restrict__ gb, const float* __restrict__ rb,
                            unsigned short* __restrict__ x_bf,
                            int* __restrict__ tok_e, float* __restrict__ tok_w,
                            int* __restrict__ counts) {
  int tkn = blockIdx.x;
  int lane = threadIdx.x;
  float acc[NEXP];
  #pragma unroll
  for (int e = 0; e < NEXP; ++e) acc[e] = 0.f;
  const float* xr = x + (long)tkn * H_DIM;
  unsigned short* xbr = x_bf + (long)tkn * H_DIM;
  for (int k = lane; k < H_DIM; k += 64) {
    float xv = xr[k];
    xbr[k] = f2bf(xv);
    #pragma unroll
    for (int e = 0; e < NEXP; ++e) acc[e] += xv * gw[e * H_DIM + k];
  }
  #pragma unroll
  for (int off = 32; off > 0; off >>= 1) {
    #pragma unroll
    for (int e = 0; e < NEXP; ++e) acc[e] += __shfl_xor(acc[e], off, 64);
  }
  if (lane == 0) {
    float s[NEXP];
    #pragma unroll
    for (int e = 0; e < NEXP; ++e)
      s[e] = 1.f / (1.f + expf(-(acc[e] + gb[e] + rb[e])));
    int e0 = 0;
    #pragma unroll
    for (int e = 1; e < NEXP; ++e) if (s[e] > s[e0]) e0 = e;
    int e1 = (e0 == 0) ? 1 : 0;
    #pragma unroll
    for (int e = 0; e < NEXP; ++e) if (e != e0 && e != e1 && s[e] > s[e1]) e1 = e;
    tok_e[2 * tkn] = e0;  tok_e[2 * tkn + 1] = e1;
    tok_w[2 * tkn] = s[e0]; tok_w[2 * tkn + 1] = s[e1];
    atomicAdd(&counts[e0], 1);
    atomicAdd(&counts[e1], 1);
  }
}

__global__ void scan_kernel(const int* __restrict__ counts, int* __restrict__ offs) {
  if (threadIdx.x == 0) {
    int o = 0;
    for (int e = 0; e < NEXP; ++e) { offs[e] = o; o += counts[e]; }
  }
}

__global__ void build_kernel(const int* __restrict__ tok_e, const float* __restrict__ tok_w,
                             const int* __restrict__ offs, int* __restrict__ cursor,
                             int* __restrict__ btok, float* __restrict__ bw,
                             int* __restrict__ tokpos) {
  int tkn = blockIdx.x * blockDim.x + threadIdx.x;
  if (tkn >= T_TOK) return;
  #pragma unroll
  for (int k = 0; k < 2; ++k) {
    int e = tok_e[2 * tkn + k];
    int p = offs[e] + atomicAdd(&cursor[e], 1);
    btok[p] = tkn;
    bw[p] = tok_w[2 * tkn + k];
    tokpos[2 * tkn + k] = p;
  }
}

__global__ void gather_kernel(const float* __restrict__ x, const int* __restrict__ btok,
                              unsigned short* __restrict__ gx) {
  int p = blockIdx.x, tid = threadIdx.x;
  int tkn = btok[p];
  const f32x4* s = (const f32x4*)(x + (long)tkn * H_DIM);
  f32x4 v0 = s[tid * 2], v1 = s[tid * 2 + 1];
  u16x8 o;
  #pragma unroll
  for (int j = 0; j < 4; ++j) { o[j] = f2bf(v0[j]); o[4 + j] = f2bf(v1[j]); }
  *(u16x8*)(gx + (long)p * H_DIM + tid * 8) = o;
}

__global__ void combine_kernel(float* __restrict__ out, const float* __restrict__ rout,
                               const int* __restrict__ tokpos) {
  int tkn = blockIdx.x, c = threadIdx.x;
  int p0 = tokpos[2 * tkn], p1 = tokpos[2 * tkn + 1];
  f32x4* o = (f32x4*)out + (long)tkn * 256;
  const f32x4* a = (const f32x4*)rout + (long)p0 * 256;
  const f32x4* b = (const f32x4*)rout + (long)p1 * 256;
  o[c] = o[c] + a[c] + b[c];
}

// ---------------------------------------------------------------- grouped GEMM1
// 256x256 tile, BK=32, 8 waves, 2-phase (round-3 proven). A bf16 via
// global_load_lds; B = fp32 weights reg-staged with in-loop cvt (T14 split).
// C = gelu(A @ B^T + bias) bf16. grid.z: 0..7 experts, 8 shared. K=1024, N=4096.
__global__ __launch_bounds__(512)
void moe_gemm1(const unsigned short* __restrict__ Ash, const unsigned short* __restrict__ Art,
               const float* __restrict__ Wsh, const float* __restrict__ Wrt,
               const float* __restrict__ bsh, const float* __restrict__ brt,
               unsigned short* __restrict__ Csh, unsigned short* __restrict__ Crt,
               const int* __restrict__ cnts, const int* __restrict__ offs) {
  __shared__ __align__(16) unsigned short lds[2][2][256][32];   // 64 KB
  const int gxd = gridDim.x;
  const int nwg = gxd * gridDim.y;
  const int wg = xcd_swizzle(blockIdx.y * gxd + blockIdx.x, nwg);
  const int mb = wg % gxd, nb = wg / gxd;
  const int z = blockIdx.z;

  const unsigned short* A;
  const float* Bp;
  const float* bias;
  unsigned short* C;
  int mcnt;
  if (z == NEXP) {
    A = Ash; Bp = Wsh; bias = bsh; C = Csh; mcnt = T_TOK;
  } else {
    const int off = offs[z];
    mcnt = cnts[z];
    A = Art + (long)off * H_DIM;
    Bp = Wrt + (long)z * F_DIM * H_DIM;
    bias = brt + z * F_DIM;
    C = Crt + (long)off * F_DIM;
  }
  if (mb * 256 >= mcnt) return;

  const int t = threadIdx.x;
  f32x4 acc[8][4] = {};
  const int nk = H_DIM >> 5;   // 32 K-steps

  f32x4 breg[4];
  const int brow = t >> 1;             // 0..255
  const int bcol = (t & 1) * 16;       // col half within 32

  auto stage_load = [&](int kt, int buf) {
    #pragma unroll
    for (int i = 0; i < 2; ++i) {
      const int row = i * 128 + (t >> 2);
      const int ch = (t & 3) * 8;
      const unsigned short* ga = A + (long)(mb * 256 + row) * H_DIM + kt * 32 + ch;
      unsigned short* la = &lds[buf][0][0][0] + i * 4096 + t * 8;
      __builtin_amdgcn_global_load_lds((const __attribute__((address_space(1))) unsigned int*)ga,
                                       (__attribute__((address_space(3))) unsigned int*)la, 16, 0, 0);
    }
    const float* gb = Bp + (long)(nb * 256 + brow) * H_DIM + kt * 32 + bcol;
    #pragma unroll
    for (int i = 0; i < 4; ++i) breg[i] = *(const f32x4*)(gb + i * 4);
  };
  auto stage_write = [&](int buf) {
    u16x8 o0, o1;
    #pragma unroll
    for (int j = 0; j < 4; ++j) {
      o0[j] = f2bf(breg[0][j]); o0[4 + j] = f2bf(breg[1][j]);
      o1[j] = f2bf(breg[2][j]); o1[4 + j] = f2bf(breg[3][j]);
    }
    *(u16x8*)&lds[buf][1][brow][bcol]     = o0;
    *(u16x8*)&lds[buf][1][brow][bcol + 8] = o1;
  };

  const int l = t & 63;
  const int w = t >> 6;                       // 8 waves: 2M x 4N
  const int wr = (w >> 2) * 128, wc = (w & 3) * 64;
  const int lr = l & 15, lk = (l >> 4) * 8;

  auto compute = [&](int buf) {
    bf16x8 a[8], b[4];
    #pragma unroll
    for (int m = 0; m < 8; ++m) a[m] = *(const bf16x8*)&lds[buf][0][wr + m * 16 + lr][lk];
    #pragma unroll
    for (int n = 0; n < 4; ++n) b[n] = *(const bf16x8*)&lds[buf][1][wc + n * 16 + lr][lk];
    #pragma unroll
    for (int m = 0; m < 8; ++m)
      #pragma unroll
      for (int n = 0; n < 4; ++n)
        acc[m][n] = __builtin_amdgcn_mfma_f32_16x16x32_bf16(a[m], b[n], acc[m][n], 0, 0, 0);
  };

  stage_load(0, 0);
  stage_write(0);
  asm volatile("s_waitcnt vmcnt(0)" ::: "memory");
  __syncthreads();
  for (int kt = 0; kt < nk - 1; ++kt) {
    const int cur = kt & 1;
    stage_load(kt + 1, cur ^ 1);   // issue A lds-loads + B f32 loads early
    compute(cur);                  // MFMA on current buffer hides load latency
    stage_write(cur ^ 1);          // cvt + ds_write after compute (T14 split)
    asm volatile("s_waitcnt vmcnt(0)" ::: "memory");
    __syncthreads();
  }
  compute((nk - 1) & 1);

  // epilogue: C/D layout col=lane&15, row=(lane>>4)*4+j (m89-verified)
  #pragma unroll
  for (int m = 0; m < 8; ++m) {
    #pragma unroll
    for (int n = 0; n < 4; ++n) {
      const int col = nb * 256 + wc + n * 16 + lr;
      const float bc = bias[col];
      #pragma unroll
      for (int j = 0; j < 4; ++j) {
        const int lrow = mb * 256 + wr + m * 16 + (l >> 4) * 4 + j;
        if (lrow >= mcnt) continue;
        float v = acc[m][n][j] + bc;
        C[(long)lrow * F_DIM + col] = f2bf(gelu_exact(v));
      }
    }
  }
}

// ---------------------------------------------------------------- grouped GEMM2
// 128x128 tile, BK=32, 4 waves, 2-phase. A = hbuf bf16 via global_load_lds;
// B = fp32 weights reg-staged. C = (A@B^T + bias)[*rowscale] f32.
// grid.z: 0..7 experts (C=rout, scaled), 8 shared (C=out). K=4096, N=1024.
__global__ __launch_bounds__(256)
void moe_gemm2(const unsigned short* __restrict__ hbuf,
               const float* __restrict__ Wsh, const float* __restrict__ Wrt,
               const float* __restrict__ bsh, const float* __restrict__ brt,
               float* __restrict__ out, float* __restrict__ rout,
               const float* __restrict__ bwgt,
               const int* __restrict__ cnts, const int* __restrict__ offs) {
  __shared__ __align__(16) unsigned short lds[2][2][128][32];   // 32 KB
  const int gxd = gridDim.x;
  const int nwg = gxd * gridDim.y;
  const int wg = xcd_swizzle(blockIdx.y * gxd + blockIdx.x, nwg);
  const int mb = wg % gxd, nb = wg / gxd;
  const int z = blockIdx.z;

  const unsigned short* A;
  const float* Bp;
  const float* bias;
  float* C;
  const float* rs = nullptr;
  int mcnt;
  if (z == NEXP) {
    A = hbuf; Bp = Wsh; bias = bsh; C = out; mcnt = T_TOK;
  } else {
    const int off = offs[z];
    mcnt = cnts[z];
    A = hbuf + ((long)T_TOK + off) * F_DIM;
    Bp = Wrt + (long)z * H_DIM * F_DIM;
    bias = brt + z * H_DIM;
    C = rout + (long)off * H_DIM;
    rs = bwgt + off;
  }
  if (mb * 128 >= mcnt) return;

  const int t = threadIdx.x;
  f32x4 acc[4][4] = {};
  const int nk = F_DIM >> 5;   // 128 K-steps

  f32x4 breg[4];
  const int brow = t >> 1;             // 0..127
  const int bcol = (t & 1) * 16;

  auto stage_load = [&](int kt, int buf) {
    #pragma unroll
    for (int i = 0; i < 2; ++i) {
      const int row = i * 64 + (t >> 2);
      const int ch = (t & 3) * 8;
      const unsigned short* ga = A + (long)(mb * 128 + row) * F_DIM + kt * 32 + ch;
      unsigned short* la = &lds[buf][0][0][0] + i * 2048 + t * 8;
      __builtin_amdgcn_global_load_lds((const __attribute__((address_space(1))) unsigned int*)ga,
                                       (__attribute__((address_space(3))) unsigned int*)la, 16, 0, 0);
    }
    const float* gb = Bp + (long)(nb * 128 + brow) * F_DIM + kt * 32 + bcol;
    #pragma unroll
    for (int i = 0; i < 4; ++i) breg[i] = *(const f32x4*)(gb + i * 4);
  };
  auto stage_write = [&](int buf) {
    u16x8 o0, o1;
    #pragma unroll
    for (int j = 0; j < 4; ++j) {
      o0[j] = f2bf(breg[0][j]); o0[4 + j] = f2bf(breg[1][j]);
      o1[j] = f2bf(breg[2][j]); o1[4 + j] = f2bf(breg[3][j]);
    }
    *(u16x8*)&lds[buf][1][brow][bcol]     = o0;
    *(u16x8*)&lds[buf][1][brow][bcol + 8] = o1;
  };

  const int l = t & 63;
  const int w = t >> 6;
  const int wr = (w >> 1) * 64, wc = (w & 1) * 64;
  const int lr = l & 15, lk = (l >> 4) * 8;

  auto compute = [&](int buf) {
    bf16x8 a[4], b[4];
    #pragma unroll
    for (int m = 0; m < 4; ++m) a[m] = *(const bf16x8*)&lds[buf][0][wr + m * 16 + lr][lk];
    #pragma unroll
    for (int n = 0; n < 4; ++n) b[n] = *(const bf16x8*)&lds[buf][1][wc + n * 16 + lr][lk];
    #pragma unroll
    for (int m = 0; m < 4; ++m)
      #pragma unroll
      for (int n = 0; n < 4; ++n)
        acc[m][n] = __builtin_amdgcn_mfma_f32_16x16x32_bf16(a[m], b[n], acc[m][n], 0, 0, 0);
  };

  stage_load(0, 0);
  stage_write(0);
  asm volatile("s_waitcnt vmcnt(0)" ::: "memory");
  __syncthreads();
  for (int kt = 0; kt < nk - 1; ++kt) {
    const int cur = kt & 1;
    stage_load(kt + 1, cur ^ 1);
    compute(cur);
    stage_write(cur ^ 1);
    asm volatile("s_waitcnt vmcnt(0)" ::: "memory");
    __syncthreads();
  }
  compute((nk - 1) & 1);

  const bool has_rs = (z != NEXP);
  #pragma unroll
  for (int m = 0; m < 4; ++m) {
    #pragma unroll
    for (int n = 0; n < 4; ++n) {
      const int col = nb * 128 + wc + n * 16 + lr;
      const float bc = bias[col];
      #pragma unroll
      for (int j = 0; j < 4; ++j) {
        const int lrow = mb * 128 + wr + m * 16 + (l >> 4) * 4 + j;
        if (lrow >= mcnt) continue;
        float v = acc[m][n][j] + bc;
        if (has_rs) v *= rs[lrow];
        C[(long)lrow * H_DIM + col] = v;
      }
    }
  }
}

// ---------------------------------------------------------------- host

extern "C" void kernel_launch(void* const* d_in, const int* in_sizes, int n_in,
                              void* d_out, int out_size, void* d_ws, size_t ws_size,
                              hipStream_t stream) {
  const float* x   = (const float*)d_in[0];
  const float* gw  = (const float*)d_in[1];
  const float* gb  = (const float*)d_in[2];
  const float* rb  = (const float*)d_in[3];
  const float* sw1 = (const float*)d_in[4];
  const float* sb1 = (const float*)d_in[5];
  const float* sw2 = (const float*)d_in[6];
  const float* sb2 = (const float*)d_in[7];
  const float* ew1 = (const float*)d_in[8];
  const float* eb1 = (const float*)d_in[9];
  const float* ew2 = (const float*)d_in[10];
  const float* eb2 = (const float*)d_in[11];

  char* wsp = (char*)d_ws;
  size_t o = 0;
  auto alloc = [&](size_t b) -> void* {
    void* p = wsp + o;
    o = (o + b + 255) & ~(size_t)255;
    return p;
  };
  unsigned short* x_bf = (unsigned short*)alloc((size_t)T_TOK * H_DIM * 2);
  unsigned short* gx   = (unsigned short*)alloc((size_t)(RT + RPAD) * H_DIM * 2);
  unsigned short* hbuf = (unsigned short*)alloc((size_t)(T_TOK + RT + RPAD) * F_DIM * 2);
  float* rout          = (float*)alloc((size_t)RT * H_DIM * 4);
  int*   tok_e  = (int*)alloc(2 * T_TOK * 4);
  float* tok_w  = (float*)alloc(2 * T_TOK * 4);
  int*   tokpos = (int*)alloc(2 * T_TOK * 4);
  int*   btok   = (int*)alloc(RT * 4);
  float* bw     = (float*)alloc(RT * 4);
  int*   meta   = (int*)alloc(1024);
  int* counts = meta, *cursor = meta + 8, *offs = meta + 16;
  (void)ws_size; (void)in_sizes; (void)n_in; (void)out_size;

  float* out = (float*)d_out;

  zero_kernel<<<1, 64, 0, stream>>>(meta);
  gate_kernel<<<T_TOK, 64, 0, stream>>>(x, gw, gb, rb, x_bf, tok_e, tok_w, counts);
  scan_kernel<<<1, 1, 0, stream>>>(counts, offs);
  build_kernel<<<T_TOK / 256, 256, 0, stream>>>(tok_e, tok_w, offs, cursor, btok, bw, tokpos);
  gather_kernel<<<RT, 128, 0, stream>>>(x, btok, gx);

  // GEMM1: K=1024, N=4096; weights fp32 fused-converted in staging.
  moe_gemm1<<<dim3(T_TOK / 256, F_DIM / 256, NEXP + 1), 512, 0, stream>>>(
      x_bf, gx, sw1, ew1, sb1, eb1,
      hbuf, hbuf + (size_t)T_TOK * F_DIM, counts, offs);

  // GEMM2: K=4096, N=1024.
  moe_gemm2<<<dim3(T_TOK / 128, H_DIM / 128, NEXP + 1), 256, 0, stream>>>(
      hbuf, sw2, ew2, sb2, eb2, out, rout, bw, counts, offs);

  combine_kernel<<<T_TOK, 256, 0, stream>>>(out, rout, tokpos);
}